// Round 3
// baseline (129.522 us; speedup 1.0000x reference)
//
#include <hip/hip_runtime.h>
#include <stdint.h>
#include <math.h>

#define NROWS 8192
#define DDIM  256
#define BM    64
#define BN    128
#define GJ    8                         // column groups (grid.y)
#define COLS_PER_GROUP (NROWS / GJ)     // 1024
#define NJT   (COLS_PER_GROUP / BN)     // 8 column tiles per block
#define NIV   4                         // 256 k / BK=64
#define NP    (NJT * NIV)               // 32 staging intervals

constexpr float INV_T  = 1.0f / 0.07f;  // fixed LSE max M0 = 1/T (|logit| <= 1/T)
constexpr float LOG2E  = 1.44269504f;
constexpr float K1     = INV_T * LOG2E; // exp2 arg: fma(acc, K1, -K1)

typedef __bf16 bf16x8 __attribute__((ext_vector_type(8)));
typedef float  f32x4  __attribute__((ext_vector_type(4)));

__device__ __forceinline__ void async_copy16(const uint16_t* g, uint16_t* l) {
    __builtin_amdgcn_global_load_lds(
        (const __attribute__((address_space(1))) uint32_t*)g,
        (__attribute__((address_space(3))) uint32_t*)l, 16, 0, 0);
}

__device__ inline uint16_t f2bf(float f) {
    uint32_t u = __float_as_uint(f);
    u += 0x7fffu + ((u >> 16) & 1u);    // RNE
    return (uint16_t)(u >> 16);
}

// Kernel 1: normalize each row to unit length, emit bf16. One wave per row.
__global__ __launch_bounds__(256) void norm_convert_kernel(
    const float* __restrict__ fq, const float* __restrict__ fk,
    uint16_t* __restrict__ qb, uint16_t* __restrict__ kb)
{
    const int wave = threadIdx.x >> 6;
    const int lane = threadIdx.x & 63;
    const int row  = blockIdx.x * 4 + wave;

    const float* src; uint16_t* dstb;
    if (row < NROWS) {
        src = fq + (size_t)row * DDIM; dstb = qb + (size_t)row * DDIM;
    } else {
        int r = row - NROWS;
        src = fk + (size_t)r * DDIM; dstb = kb + (size_t)r * DDIM;
    }

    float4 v = ((const float4*)src)[lane];
    float ss = v.x*v.x + v.y*v.y + v.z*v.z + v.w*v.w;
    #pragma unroll
    for (int m = 1; m < 64; m <<= 1) ss += __shfl_xor(ss, m, 64);
    float r = rsqrtf(ss);

    ushort4 o;
    o.x = f2bf(v.x * r); o.y = f2bf(v.y * r); o.z = f2bf(v.z * r); o.w = f2bf(v.w * r);
    ((ushort4*)dstb)[lane] = o;
}

// Kernel 2: fused GEMM + fixed-max sum-of-exp over this block's 1024-col group.
// Geometry: BM=64 x BN=128 tile, 512 threads / 8 waves in 2x4 -> only 2 waves
// share each wc column-slice, halving redundant B ds_reads vs round 2 (which
// made the LDS pipe the floor: 4-way redundancy ~ 19.6us/CU > 16.6us MFMA).
// Q in registers (aq[2][8]=64 VGPR, proven no-spill). K streams through a
// ring of 4 x 16KiB BK=64 buffers, counted vmcnt(4), prefetch distance 3,
// 32 barriers with 8 MFMA each. LDS swizzle: chunk c of row r stored at
// c^(r&7); rows are 128B so reads cover all 32 banks per 8-lane phase.
__global__ __launch_bounds__(512, 2) void nce_main_kernel(
    const uint16_t* __restrict__ qb, const uint16_t* __restrict__ kb,
    float* __restrict__ lpT, float* __restrict__ gpl)
{
    __shared__ __align__(16) uint16_t lds_k[4 * 8192];  // 4 ring bufs x 16 KiB = 64 KiB

    const int tid    = threadIdx.x;
    const int wave   = tid >> 6;
    const int lane   = tid & 63;
    const int quad   = lane >> 4;
    const int lanelo = lane & 15;
    const int wr     = wave >> 2;       // 0..1 (32-row slice)
    const int wc     = wave & 3;        // 0..3 (32-col slice)
    const int rowBase      = blockIdx.x * BM;
    const int colGroupBase = blockIdx.y * COLS_PER_GROUP;

    // ---- Q fragments straight into registers (64 VGPR), loaded exactly once.
    bf16x8 aq[2][8];
    #pragma unroll
    for (int mt = 0; mt < 2; ++mt) {
        const uint16_t* qrow =
            qb + (size_t)(rowBase + wr * 32 + mt * 16 + lanelo) * DDIM + quad * 8;
        #pragma unroll
        for (int kk = 0; kk < 8; ++kk)
            aq[mt][kk] = *(const bf16x8*)(qrow + kk * 32);
    }
    // Drain aq loads so every later vmcnt(N) counts ONLY the K DMAs (FIFO
    // counting must not be polluted; memory clobber pins loads above, DMAs below).
    asm volatile("s_waitcnt vmcnt(0)" ::: "memory");

    // ---- K staging lane constants. Interval buffer = [128 rows][64 k] bf16,
    // 1024 chunks of 16B. Linear chunk S -> row r=S>>3, pos p8=S&7, and the
    // SOURCE chunk is p8^(r&7) (involution; read side applies the same XOR).
    // Per wave: 2 loads/interval (j=0: rows wave*8+(lane>>3), j=1: +64).
    const int r0 = wave * 8 + (lane >> 3);              // wave*8 % 8 == 0
    const int c0 = (lane & 7) ^ ((lane >> 3) & 7);      // same for j=0 and j=1
    const uint16_t* kbase0 = kb + (size_t)(colGroupBase + r0)      * DDIM + c0 * 8;
    const uint16_t* kbase1 = kb + (size_t)(colGroupBase + r0 + 64) * DDIM + c0 * 8;

    // ---- Prologue: intervals 0..2 into ring bufs 0..2 (6 loads in flight/wave).
    #pragma unroll
    for (int p = 0; p < 3; ++p) {
        uint16_t* ld = lds_k + (p << 13) + (wave << 9);
        async_copy16(kbase0 + (p << 6), ld);            // jt=0: off = iv*64
        async_copy16(kbase1 + (p << 6), ld + 4096);
    }

    // Read offsets (uint16 units): row rk=wc*32+nt*16+lanelo, chunk kk*4+quad,
    // stored at pos (kk*4+quad)^(rk&7); rk&7 == lanelo&7.
    int bvoff[2][2];
    #pragma unroll
    for (int kk = 0; kk < 2; ++kk)
        #pragma unroll
        for (int nt = 0; nt < 2; ++nt) {
            int rk = wc * 32 + nt * 16 + lanelo;
            bvoff[kk][nt] = rk * 64 + ((kk * 4 + quad) ^ (lanelo & 7)) * 8;
        }

    float l_run[8];
    #pragma unroll
    for (int i = 0; i < 8; ++i) l_run[i] = 0.f;

    for (int jt = 0; jt < NJT; ++jt) {
        f32x4 acc[2][2];
        #pragma unroll
        for (int mt = 0; mt < 2; ++mt)
            #pragma unroll
            for (int nt = 0; nt < 2; ++nt)
                acc[mt][nt] = (f32x4){0.f, 0.f, 0.f, 0.f};

        #pragma unroll
        for (int iv = 0; iv < NIV; ++iv) {
            const int p = jt * NIV + iv;

            // Outstanding: intervals p,p+1,p+2 (2 loads each). vmcnt(4)
            // completes the 2 oldest = interval p; then publish via barrier.
            asm volatile("s_waitcnt vmcnt(4)" ::: "memory");
            asm volatile("s_barrier" ::: "memory");

            // Issue interval p+3 into buf (p+3)&3 (its last readers passed the
            // barrier). Tail issues wrap the source index: never read, drained
            // by the final __syncthreads.
            {
                const int npm = (p + 3) & (NP - 1);
                const int off = ((npm >> 2) << 15) + ((npm & 3) << 6); // jt*32768 + iv*64
                uint16_t* ld = lds_k + (((p + 3) & 3) << 13) + (wave << 9);
                async_copy16(kbase0 + off, ld);
                async_copy16(kbase1 + off, ld + 4096);
            }

            // Compute interval p: 2 sub-chunks of K=32; 2 ds_read_b128 + 4 MFMA each.
            const int bufo = (p & 3) << 13;
            #pragma unroll
            for (int kk = 0; kk < 2; ++kk) {
                bf16x8 bv0 = *(const bf16x8*)&lds_k[bufo + bvoff[kk][0]];
                bf16x8 bv1 = *(const bf16x8*)&lds_k[bufo + bvoff[kk][1]];
                const int ka = iv * 2 + kk;
                __builtin_amdgcn_s_setprio(1);
                #pragma unroll
                for (int mt = 0; mt < 2; ++mt) {
                    acc[mt][0] = __builtin_amdgcn_mfma_f32_16x16x32_bf16(
                        aq[mt][ka], bv0, acc[mt][0], 0, 0, 0);
                    acc[mt][1] = __builtin_amdgcn_mfma_f32_16x16x32_bf16(
                        aq[mt][ka], bv1, acc[mt][1], 0, 0, 0);
                }
                __builtin_amdgcn_s_setprio(0);
            }
        }

        // Epilogue: fixed-max exp accumulate (registers only).
        const int colT = colGroupBase + jt * BN;
        int gcol[2];
        #pragma unroll
        for (int nt = 0; nt < 2; ++nt) gcol[nt] = colT + wc * 32 + nt * 16 + lanelo;
        #pragma unroll
        for (int mt = 0; mt < 2; ++mt) {
            #pragma unroll
            for (int rg = 0; rg < 4; ++rg) {
                int grow = rowBase + wr * 32 + mt * 16 + quad * 4 + rg;
                float s = 0.f;
                #pragma unroll
                for (int nt = 0; nt < 2; ++nt) {
                    float a = acc[mt][nt][rg];
                    float e = exp2f(fmaf(a, K1, -K1));
                    if (grow == gcol[nt]) { lpT[grow] = a * INV_T; e = 0.f; }  // diag ~e^-157
                    s += e;
                }
                l_run[mt * 4 + rg] += s;
            }
        }
    }

    // Cross-lane reduce over the 16 lanelo lanes (same row, different cols).
    #pragma unroll
    for (int i = 0; i < 8; ++i) {
        float v = l_run[i];
        v += __shfl_xor(v, 1, 64);
        v += __shfl_xor(v, 2, 64);
        v += __shfl_xor(v, 4, 64);
        v += __shfl_xor(v, 8, 64);
        l_run[i] = v;
    }

    // Drain wrap prefetch DMAs and resync all waves before reusing lds_k.
    __syncthreads();

    float* pl = (float*)lds_k;      // 256 floats scratch (4 wc slices x 64 rows)
    if (lanelo == 0) {
        #pragma unroll
        for (int mt = 0; mt < 2; ++mt)
            #pragma unroll
            for (int rg = 0; rg < 4; ++rg) {
                int lr = wr * 32 + mt * 16 + quad * 4 + rg;
                pl[wc * 64 + lr] = l_run[mt * 4 + rg];
            }
    }
    __syncthreads();
    if (tid < 64) {
        float L = pl[tid] + pl[64 + tid] + pl[128 + tid] + pl[192 + tid];
        gpl[(size_t)blockIdx.y * NROWS + rowBase + tid] = L;
    }
}

// Kernel 3: merge GJ partial sums + l_pos; loss = M0 + log(L) - l_pos/T.
__global__ __launch_bounds__(256) void finalize_kernel(
    const float* __restrict__ gpl, const float* __restrict__ lpT,
    float* __restrict__ out)
{
    int t = blockIdx.x * 256 + threadIdx.x;
    if (t >= NROWS) return;
    float L = 0.f;
    #pragma unroll
    for (int g = 0; g < GJ; ++g) L += gpl[g * NROWS + t];
    float lp = lpT[t];
    L += __expf(lp - INV_T);
    out[t] = INV_T + __logf(L) - lp;
}

extern "C" void kernel_launch(void* const* d_in, const int* in_sizes, int n_in,
                              void* d_out, int out_size, void* d_ws, size_t ws_size,
                              hipStream_t stream) {
    const float* fq = (const float*)d_in[0];
    const float* fk = (const float*)d_in[1];
    char* ws = (char*)d_ws;
    // layout: qb 4MB | kb 4MB | lpT 32KB | gpl 256KB
    uint16_t* qb  = (uint16_t*)(ws);
    uint16_t* kb  = (uint16_t*)(ws + 4194304);
    float*    lpT = (float*)(ws + 8388608);
    float*    gpl = (float*)(ws + 8421376);

    norm_convert_kernel<<<(2 * NROWS) / 4, 256, 0, stream>>>(fq, fk, qb, kb);
    dim3 grid(NROWS / BM, GJ);
    nce_main_kernel<<<grid, 512, 0, stream>>>(qb, kb, lpT, gpl);
    finalize_kernel<<<NROWS / 256, 256, 0, stream>>>(gpl, lpT, (float*)d_out);
}